// Round 5
// baseline (274.541 us; speedup 1.0000x reference)
//
#include <hip/hip_runtime.h>
#include <hip/hip_bf16.h>
#include <cstdint>
#include <cstddef>

#define B_  16
#define S_  512
#define E_  768
#define NH_ 12
#define D_  64
#define M_  (B_*S_)   // 8192

typedef unsigned short u16;
typedef __attribute__((ext_vector_type(4))) float f32x4;
typedef __attribute__((ext_vector_type(8))) short bf16x8;

#define LOG2E 1.4426950408889634f

__device__ __forceinline__ u16 f2bf(float f){
  union { float fv; uint32_t u; } v; v.fv = f;
  uint32_t u = v.u;
  uint32_t r = u + 0x7fffu + ((u >> 16) & 1u);   // RNE
  return (u16)(r >> 16);
}

// async global->LDS, 16B per lane, dest = (wave-uniform) base + lane*16
__device__ __forceinline__ void gload_lds16(const u16* g, u16* l){
  __builtin_amdgcn_global_load_lds(
      (const __attribute__((address_space(1))) void*)g,
      (__attribute__((address_space(3))) void*)l, 16, 0, 0);
}

// pack 8 fp32 -> 8 bf16 RNE (k-ascending, low u16 first)
__device__ __forceinline__ uint4 pack8(const float4& a, const float4& b){
  float2 p01; p01.x = a.x; p01.y = a.y;
  float2 p23; p23.x = a.z; p23.y = a.w;
  float2 p45; p45.x = b.x; p45.y = b.y;
  float2 p67; p67.x = b.z; p67.y = b.w;
  __hip_bfloat162 h0 = __float22bfloat162_rn(p01);
  __hip_bfloat162 h1 = __float22bfloat162_rn(p23);
  __hip_bfloat162 h2 = __float22bfloat162_rn(p45);
  __hip_bfloat162 h3 = __float22bfloat162_rn(p67);
  uint4 r;
  r.x = *reinterpret_cast<const unsigned int*>(&h0);
  r.y = *reinterpret_cast<const unsigned int*>(&h1);
  r.z = *reinterpret_cast<const unsigned int*>(&h2);
  r.w = *reinterpret_cast<const unsigned int*>(&h3);
  return r;
}

// ---------------- prep: W transpose only ----------------
__global__ __launch_bounds__(256) void prep_kernel(
    const float* __restrict__ Wq, const float* __restrict__ Wk,
    const float* __restrict__ Wv, u16* __restrict__ WtBase)
{
  __shared__ float t[32][33];
  const int tt = blockIdx.x;               // 0..1727 = 24*24*3
  int z = tt / 576, rem = tt % 576;
  int byi = rem / 24, bxi = rem % 24;
  const float* W = (z == 0) ? Wq : ((z == 1) ? Wk : Wv);
  u16* Wt = WtBase + (size_t)z * E_ * E_;
  int bx0 = bxi * 32, by0 = byi * 32;
  int tx = threadIdx.x & 31, ty = threadIdx.x >> 5;
  #pragma unroll
  for (int i = 0; i < 32; i += 8)
    t[ty + i][tx] = W[(size_t)(by0 + ty + i) * E_ + bx0 + tx];
  __syncthreads();
  #pragma unroll
  for (int i = 0; i < 32; i += 8)
    Wt[(size_t)(bx0 + ty + i) * E_ + by0 + tx] = f2bf(t[tx][ty + i]);
}

// ---------------- R11: fully fused QKV-GEMM + flash attention ----------------
// Evidence R0-R10: EVERY dispatch runs at dur ~= (FETCH+WRITE)/0.84 TB/s
// regardless of schedule (serial / dbuf / counted-vmcnt all tie). Only lever:
// total bytes. This kernel removes the Q/K/V HBM round-trip entirely
// (37.7 MB write + 37.7 MB read ~= 90 us on that line).
// One block per (b,h): 512 thr / 8 waves; wave w owns seq rows w*64..+63.
//   Phase G: 3 GEMMs (Q,K,V), M=64/wave, N=64, K=768. A = X[b] fp32 direct
//     (every byte used once; L2-resident via XCD swizzle), pack to bf16 in
//     regs. B = Wt head-slice via proven gload_lds+pre-swizzled-source path,
//     double-buffered, 36 one-barrier iterations.
//   Q acc -> per-wave LDS bounce (chunked layout) -> qf regs.
//   K acc -> lK (64 KB, identity chunk layout = the staged layout attn used).
//   V acc -> lV (64 KB, transposed V^T layout, b64 writes).
//   Phase A: the proven attention loop, K/V/P entirely in LDS, no barriers.
// LDS: lK 64K | lV 64K (aliases per-wave Q-scratch) | lB/lP 16K | bias 2K.
__global__ __launch_bounds__(512) void fused_kernel(
    const float* __restrict__ X, const u16* __restrict__ WtBase,
    const float* __restrict__ bq, const float* __restrict__ bk, const float* __restrict__ bv,
    const float* __restrict__ mask, float* __restrict__ out)
{
  extern __shared__ u16 lds[];
  u16* lK  = lds;                  // 32768 u16: chunk = key_tile*8 + ks*4 + nt
  u16* lV  = lds + 32768;          // 32768 u16: chunk = s_tile*8 + ks2*4 + nd (V^T); early: per-wave Q scratch
  u16* lBP = lds + 65536;          // 8192 u16: GEMM B dbuf (2x4096) / attn lP (8x1024)
  float* biasS = (float*)(lds + 73728);  // 512 floats

  // XCD-locality swizzle: xcd = blk&7 handles b in {2*xcd, 2*xcd+1}, all 12 h
  const int blk = blockIdx.x;
  const int xcd = blk & 7, idx = blk >> 3;          // idx 0..23
  const int b = xcd * 2 + (idx >= 12 ? 1 : 0);
  const int h = (idx >= 12) ? (idx - 12) : idx;

  const int tid = threadIdx.x, lane = tid & 63, wave = tid >> 6;
  const int col0 = lane & 15, quad = lane >> 4;
  const int rslot = quad*16 + (col0 ^ (quad << 1));
  const int oct_l = lane >> 4;
  const int row_l = (lane & 15) ^ (oct_l << 1);     // pre-swizzled gload source row
  const float C1 = 0.125f * LOG2E;

  if (tid < S_) biasS[tid] = mask[b * S_ + tid] * (-1.0e9f * LOG2E);

  const float* Xrow = X + ((size_t)(b * S_ + wave * 64)) * E_;

  // ---- phase G: Q,K,V GEMMs ----
  f32x4 acc[4][4];
  #pragma unroll
  for (int i = 0; i < 4; ++i)
    #pragma unroll
    for (int j = 0; j < 4; ++j) acc[i][j] = (f32x4){0.f,0.f,0.f,0.f};

  bf16x8 qf[4][2];   // persists into attention

  auto stageB = [&](int t, int buf){
    int zt = t / 12, kt = t % 12;
    const u16* src = WtBase + (size_t)zt * E_ * E_
                   + (size_t)(h*64 + (wave>>1)*16 + row_l) * E_
                   + kt*64 + (wave & 1)*32 + oct_l*8;
    gload_lds16(src, lBP + buf*4096 + wave*512);
  };

  stageB(0, 0);

  #pragma unroll 1
  for (int t = 0; t < 36; ++t){
    __syncthreads();                      // drains buf[t&1] staging; retires prev reads
    if (t < 35) stageB(t + 1, (t + 1) & 1);
    const int kt = t % 12;
    const u16* lb = lBP + (t & 1) * 4096;
    #pragma unroll
    for (int ks = 0; ks < 2; ++ks){
      bf16x8 bfr[4], af[4];
      #pragma unroll
      for (int ni = 0; ni < 4; ++ni)
        bfr[ni] = *reinterpret_cast<const bf16x8*>(&lb[(ni*2 + ks)*512 + rslot*8]);
      #pragma unroll
      for (int mi = 0; mi < 4; ++mi){
        const float* p = Xrow + (size_t)(mi*16 + col0) * E_ + kt*64 + ks*32 + quad*8;
        float4 a0 = *reinterpret_cast<const float4*>(p);
        float4 a1 = *reinterpret_cast<const float4*>(p + 4);
        uint4 u = pack8(a0, a1);
        af[mi] = *reinterpret_cast<const bf16x8*>(&u);
      }
      #pragma unroll
      for (int mi = 0; mi < 4; ++mi)
        #pragma unroll
        for (int ni = 0; ni < 4; ++ni)
          acc[mi][ni] = __builtin_amdgcn_mfma_f32_16x16x32_bf16(af[mi], bfr[ni], acc[mi][ni], 0, 0, 0);
    }
    if (kt == 11){                        // finish output z
      const int z = t / 12;
      const float* bz = (z == 0) ? bq : ((z == 1) ? bk : bv);
      float bvv[4];
      #pragma unroll
      for (int ni = 0; ni < 4; ++ni) bvv[ni] = bz[h*64 + ni*16 + col0];
      if (z < 2){
        // K[row][d] chunked layout (Q scratch uses lV region, own-wave only)
        u16* dst = (z == 0) ? lV : lK;
        #pragma unroll
        for (int mi = 0; mi < 4; ++mi)
          #pragma unroll
          for (int ni = 0; ni < 4; ++ni){
            int chunk = (z == 0) ? (wave*8 + mi*2 + (ni>>1))
                                 : (wave*8 + (ni>>1)*4 + mi);
            int base = chunk*512 + (((ni&1)*2 + (col0>>3))*16 + quad*4)*8 + (col0 & 7);
            #pragma unroll
            for (int r = 0; r < 4; ++r)
              dst[base + r*8] = f2bf(acc[mi][ni][r] + bvv[ni]);
          }
        if (z == 0){
          #pragma unroll
          for (int g = 0; g < 4; ++g)
            #pragma unroll
            for (int ks = 0; ks < 2; ++ks)
              qf[g][ks] = *reinterpret_cast<const bf16x8*>(&lV[(wave*8 + g*2 + ks)*512 + lane*8]);
        }
      } else {
        // V^T[d][s]: lane's r=0..3 are 4 consecutive s -> b64 writes
        #pragma unroll
        for (int mi = 0; mi < 4; ++mi)
          #pragma unroll
          for (int ni = 0; ni < 4; ++ni){
            int chunk = wave*8 + ((mi & 2) >> 1)*4 + ni;
            int off = chunk*512 + (((mi&1)*2 + (quad>>1))*16 + col0)*8 + (quad & 1)*4;
            float2 ab; ab.x = acc[mi][ni][0] + bvv[ni]; ab.y = acc[mi][ni][1] + bvv[ni];
            float2 cd; cd.x = acc[mi][ni][2] + bvv[ni]; cd.y = acc[mi][ni][3] + bvv[ni];
            __hip_bfloat162 h01 = __float22bfloat162_rn(ab);
            __hip_bfloat162 h23 = __float22bfloat162_rn(cd);
            uint2 pw;
            pw.x = *reinterpret_cast<unsigned int*>(&h01);
            pw.y = *reinterpret_cast<unsigned int*>(&h23);
            *reinterpret_cast<uint2*>(&lV[off]) = pw;
          }
      }
      #pragma unroll
      for (int i = 0; i < 4; ++i)
        #pragma unroll
        for (int j = 0; j < 4; ++j) acc[i][j] = (f32x4){0.f,0.f,0.f,0.f};
    }
  }
  __syncthreads();   // lK/lV complete & visible; lBP free for lP reuse

  // ---- phase A: attention from LDS (no barriers) ----
  f32x4 o[4][4];
  #pragma unroll
  for (int g = 0; g < 4; ++g)
    #pragma unroll
    for (int i = 0; i < 4; ++i) o[g][i] = (f32x4){0.f,0.f,0.f,0.f};
  float psum[4] = {0.f, 0.f, 0.f, 0.f};
  u16* lP = lBP + wave * 1024;            // per-wave, reused across g (DS in-order)

  #pragma unroll 1
  for (int st = 0; st < 8; ++st){
    bf16x8 kf[2][4], vf[2][4];
    #pragma unroll
    for (int ks = 0; ks < 2; ++ks)
      #pragma unroll
      for (int nt = 0; nt < 4; ++nt)
        kf[ks][nt] = *reinterpret_cast<const bf16x8*>(&lK[(st*8 + ks*4 + nt)*512 + lane*8]);
    #pragma unroll
    for (int ks2 = 0; ks2 < 2; ++ks2)
      #pragma unroll
      for (int nd = 0; nd < 4; ++nd)
        vf[ks2][nd] = *reinterpret_cast<const bf16x8*>(&lV[(st*8 + ks2*4 + nd)*512 + lane*8]);
    float4 bb[4];
    #pragma unroll
    for (int nt = 0; nt < 4; ++nt)
      bb[nt] = *reinterpret_cast<const float4*>(&biasS[st*64 + nt*16 + quad*4]);

    #pragma unroll
    for (int g = 0; g < 4; ++g){
      f32x4 sc[4];
      #pragma unroll
      for (int nt = 0; nt < 4; ++nt) sc[nt] = (f32x4){0.f,0.f,0.f,0.f};
      #pragma unroll
      for (int ks = 0; ks < 2; ++ks)
        #pragma unroll
        for (int nt = 0; nt < 4; ++nt)
          sc[nt] = __builtin_amdgcn_mfma_f32_16x16x32_bf16(kf[ks][nt], qf[g][ks], sc[nt], 0, 0, 0);
      #pragma unroll
      for (int nt = 0; nt < 4; ++nt){
        float p0 = exp2f(sc[nt][0] * C1 + bb[nt].x);
        float p1 = exp2f(sc[nt][1] * C1 + bb[nt].y);
        float p2 = exp2f(sc[nt][2] * C1 + bb[nt].z);
        float p3 = exp2f(sc[nt][3] * C1 + bb[nt].w);
        psum[g] += (p0 + p1) + (p2 + p3);
        float2 ab; ab.x = p0; ab.y = p1;
        float2 cd; cd.x = p2; cd.y = p3;
        __hip_bfloat162 h01 = __float22bfloat162_rn(ab);
        __hip_bfloat162 h23 = __float22bfloat162_rn(cd);
        uint2 pw;
        pw.x = *reinterpret_cast<unsigned int*>(&h01);
        pw.y = *reinterpret_cast<unsigned int*>(&h23);
        int addr = (nt >> 1)*512 + (((nt & 1)*2 + (quad >> 1))*16 + col0)*8 + (quad & 1)*4;
        *reinterpret_cast<uint2*>(&lP[addr]) = pw;
      }
      #pragma unroll
      for (int ks2 = 0; ks2 < 2; ++ks2){
        bf16x8 pf = *reinterpret_cast<const bf16x8*>(&lP[ks2*512 + lane*8]);
        #pragma unroll
        for (int nd = 0; nd < 4; ++nd)
          o[g][nd] = __builtin_amdgcn_mfma_f32_16x16x32_bf16(pf, vf[ks2][nd], o[g][nd], 0, 0, 0);
      }
    }
  }

  // epilogue
  #pragma unroll
  for (int g = 0; g < 4; ++g){
    float tot = psum[g];
    tot += __shfl_xor(tot, 16, 64);
    tot += __shfl_xor(tot, 32, 64);
    #pragma unroll
    for (int r = 0; r < 4; ++r){
      int s = wave*64 + g*16 + quad*4 + r;
      float lr = __shfl(tot, (lane & 48) | (quad*4 + r), 64);
      float inv = 1.0f / lr;
      #pragma unroll
      for (int nd = 0; nd < 4; ++nd){
        int d = nd*16 + col0;
        out[((size_t)b * S_ + s) * E_ + h*D_ + d] = o[g][nd][r] * inv;
      }
    }
  }
}

extern "C" void kernel_launch(void* const* d_in, const int* in_sizes, int n_in,
                              void* d_out, int out_size, void* d_ws, size_t ws_size,
                              hipStream_t stream){
  const float* X    = (const float*)d_in[0];
  const float* mask = (const float*)d_in[1];
  const float* Wq   = (const float*)d_in[2];
  const float* bq   = (const float*)d_in[3];
  const float* Wk   = (const float*)d_in[4];
  const float* bk   = (const float*)d_in[5];
  const float* Wv   = (const float*)d_in[6];
  const float* bv   = (const float*)d_in[7];
  float* out = (float*)d_out;

  u16* Wt = (u16*)d_ws;   // 3 x 768 x 768 bf16 = 3.5 MB

  prep_kernel<<<1728, 256, 0, stream>>>(Wq, Wk, Wv, Wt);
  fused_kernel<<<192, 512, 149504, stream>>>(X, Wt, bq, bk, bv, mask, out);
}